// Round 8
// baseline (204.209 us; speedup 1.0000x reference)
//
#include <hip/hip_runtime.h>
#include <hip/hip_bf16.h>
#include <math.h>

// Exact numpy rounding everywhere: no FMA contraction in this file.
#pragma clang fp contract(off)

#define NPIX 4096      // 64*64
#define MAXB 32
#define NB   4
#define ROI_N 8388608          // 4*32*8*64*128 elements per roi tensor
#define OTOT (ROI_N / 8)       // 8-channel work items per roi tensor

typedef float f32x4 __attribute__((ext_vector_type(4)));   // clang vector: OK for nontemporal builtins

// ---------------------------------------------------------------------------
// Kernel 1: score/box reconstruct + serial NMS (one block per batch), LAZY
// suppression: each lane caches a validated "head" candidate in registers.
// Fast path per iteration = 1 IoU + butterfly + 1 barrier. The 16-wide
// argmax (static-unrolled, latches head box into named regs) runs only when
// the head dies; a new head is validated vs the full winner history (s_win).
// ---------------------------------------------------------------------------
__global__ __launch_bounds__(256) void nms_kernel(const float* __restrict__ bbox,
                                                  float* __restrict__ out_nms,
                                                  float* __restrict__ params,
                                                  float* __restrict__ out_w,
                                                  float* __restrict__ out_hh)
{
    const int b = blockIdx.x;
    const int t = threadIdx.x;

    __shared__ float s_box[NPIX][4];     // 64 KB, winner broadcast lookup
    __shared__ float s_win[MAXB][5];     // raw winner boxes + area (history)
    __shared__ float s_sel[MAXB][4];     // keep-applied boxes for epilogue
    __shared__ float s_red[2][4][2];     // [buf][wave][score, idx]

    float rs[16], rx1[16], ry1[16], rx2[16], ry2[16], rar[16];

    const float* src = bbox + (size_t)b * NPIX * 5;

    #pragma unroll
    for (int i = 0; i < 16; ++i) {
        int p = i * 256 + t;
        int y = p >> 6, x = p & 63;
        float c0 = src[p * 5 + 0];
        float c1 = src[p * 5 + 1];
        float c2 = src[p * 5 + 2];
        float c3 = src[p * 5 + 3];
        float c4 = src[p * 5 + 4];
        float sc = 1.0f / (1.0f + expf(-c0));   // keep formulation byte-identical
        float x1 = 8.0f * ((float)x - c1);
        float y1 = 8.0f * ((float)y - c2);
        float x2 = 8.0f * ((float)x + c3);
        float y2 = 8.0f * ((float)y + c4);
        rs[i] = sc;
        rx1[i] = x1; ry1[i] = y1; rx2[i] = x2; ry2[i] = y2;
        rar[i] = (x2 - x1) * (y2 - y1);
        s_box[p][0] = x1; s_box[p][1] = y1; s_box[p][2] = x2; s_box[p][3] = y2;
    }
    __syncthreads();

    unsigned valid = 0xFFFFu;            // bit i <-> candidate p = i*256 + t
    float head_s; int head_p;            // lane's validated head
    float hx1, hy1, hx2, hy2, har;

    // initial head = per-lane argmax (no winners yet -> trivially validated)
    {
        float bs = -INFINITY; int bp = 0x7FFFFFFF;
        float b1 = 0.f, b2 = 0.f, b3 = 0.f, b4 = 0.f, ba = 0.f;
        #pragma unroll
        for (int i = 0; i < 16; ++i) {
            bool take = rs[i] > bs;      // strict > keeps lowest p
            bs = take ? rs[i] : bs; bp = take ? (i * 256 + t) : bp;
            b1 = take ? rx1[i] : b1; b2 = take ? ry1[i] : b2;
            b3 = take ? rx2[i] : b3; b4 = take ? ry2[i] : b4;
            ba = take ? rar[i] : ba;
        }
        head_s = bs; head_p = bp; hx1 = b1; hy1 = b2; hx2 = b3; hy2 = b4; har = ba;
    }

    for (int it = 0; it < MAXB; ++it) {
        // ---- propose validated head; global argmax ----
        float best = head_s; int bidx = head_p;
        #pragma unroll
        for (int off = 32; off; off >>= 1) {
            float ov = __shfl_xor(best, off);
            int   oi = __shfl_xor(bidx, off);
            bool take = (ov > best) || (ov == best && oi < bidx);
            best = take ? ov : best;
            bidx = take ? oi : bidx;
        }
        int buf = it & 1;
        if ((t & 63) == 0) {
            s_red[buf][t >> 6][0] = best;
            s_red[buf][t >> 6][1] = __int_as_float(bidx);
        }
        __syncthreads();                 // the ONLY barrier in the iteration
        best = s_red[buf][0][0]; bidx = __float_as_int(s_red[buf][0][1]);
        #pragma unroll
        for (int wv = 1; wv < 4; ++wv) {
            float ov = s_red[buf][wv][0];
            int   oi = __float_as_int(s_red[buf][wv][1]);
            bool take = (ov > best) || (ov == best && oi < bidx);
            best = take ? ov : best;
            bidx = take ? oi : bidx;
        }

        bool ok = (best > -INFINITY);
        int  jw = bidx;
        int  jj = min(jw, NPIX - 1);     // clamp (garbage only when !ok)
        float wx1 = s_box[jj][0], wy1 = s_box[jj][1];
        float wx2 = s_box[jj][2], wy2 = s_box[jj][3];
        float warea = (wx2 - wx1) * (wy2 - wy1);

        if (t == 0) {
            bool keep = (best >= 0.3f);  // -inf fails too
            float o0 = keep ? wx1 : 0.f, o1 = keep ? wy1 : 0.f;
            float o2 = keep ? wx2 : 0.f, o3 = keep ? wy2 : 0.f;
            float* o = out_nms + ((size_t)b * MAXB + it) * 4;
            o[0] = o0; o[1] = o1; o[2] = o2; o[3] = o3;
            s_sel[it][0] = o0; s_sel[it][1] = o1;
            s_sel[it][2] = o2; s_sel[it][3] = o3;
            if (ok) {                    // raw winner for history checks
                s_win[it][0] = wx1; s_win[it][1] = wy1;
                s_win[it][2] = wx2; s_win[it][3] = wy2; s_win[it][4] = warea;
            }
        }

        // ---- lazy head maintenance ----
        if (ok && valid) {
            bool died;
            if (head_p == jw) {
                died = true;             // selected (ref: IoU(j,j)~1 suppresses j)
            } else {
                float iw = fmaxf(fminf(hx2, wx2) - fmaxf(hx1, wx1), 0.f);
                float ih = fmaxf(fminf(hy2, wy2) - fmaxf(hy1, wy1), 0.f);
                float inter = iw * ih;
                died = __fdiv_rn(inter, har + warea - inter + 1e-9f) > 0.5f;
            }
            while (died) {
                valid &= ~(1u << (head_p >> 8));   // p = i*256+t, t<256 -> i = p>>8
                if (!valid) { head_s = -INFINITY; head_p = 0x7FFFFFFF; break; }
                // re-argmax over remaining valid, latching box into named regs
                float bs = -INFINITY; int bp = 0x7FFFFFFF;
                float b1 = 0.f, b2 = 0.f, b3 = 0.f, b4 = 0.f, ba = 0.f;
                #pragma unroll
                for (int i = 0; i < 16; ++i) {
                    float vv = ((valid >> i) & 1u) ? rs[i] : -INFINITY;
                    bool take = vv > bs;
                    bs = take ? vv : bs; bp = take ? (i * 256 + t) : bp;
                    b1 = take ? rx1[i] : b1; b2 = take ? ry1[i] : b2;
                    b3 = take ? rx2[i] : b3; b4 = take ? ry2[i] : b4;
                    ba = take ? rar[i] : ba;
                }
                head_s = bs; head_p = bp; hx1 = b1; hy1 = b2; hx2 = b3; hy2 = b4; har = ba;
                // validate vs current winner...
                {
                    float iw = fmaxf(fminf(hx2, wx2) - fmaxf(hx1, wx1), 0.f);
                    float ih = fmaxf(fminf(hy2, wy2) - fmaxf(hy1, wy1), 0.f);
                    float inter = iw * ih;
                    died = __fdiv_rn(inter, har + warea - inter + 1e-9f) > 0.5f;
                }
                // ...then vs winner history (uniform-addr LDS broadcast reads)
                if (!died) {
                    for (int v = 0; v < it; ++v) {
                        float qx1 = s_win[v][0], qy1 = s_win[v][1];
                        float qx2 = s_win[v][2], qy2 = s_win[v][3], qa = s_win[v][4];
                        float iw = fmaxf(fminf(hx2, qx2) - fmaxf(hx1, qx1), 0.f);
                        float ih = fmaxf(fminf(hy2, qy2) - fmaxf(hy1, qy1), 0.f);
                        float inter = iw * ih;
                        if (__fdiv_rn(inter, har + qa - inter + 1e-9f) > 0.5f) {
                            died = true; break;
                        }
                    }
                }
            }
        }
    }
    __syncthreads();                      // publish s_sel to epilogue

    // ---- epilogue: per-(dir, box) ROI params, once per box ----
    if (t < 64) {
        int dir = t >> 5, bx = t & 31;
        float x1 = s_sel[bx][0] * 0.125f, y1 = s_sel[bx][1] * 0.125f;  // exact /8
        float x2 = s_sel[bx][2] * 0.125f, y2 = s_sel[bx][3] * 0.125f;
        float w = x2 - x1, h = y2 - y1;
        bool is_dir = (dir == 0) ? (w >= h) : (w < h);
        if (!is_dir) { x1 = 0.f; y1 = 0.f; x2 = 0.f; y2 = 0.f; }
        w = x2 - x1; h = y2 - y1;
        bool  non_zero = (w >= 0.1f) || (h >= 0.1f);
        float bw = (w <= 0.f) ? 1e-4f : w;
        float bh = (h <= 0.f) ? 1e-4f : h;
        float ratio = non_zero ? ((dir == 0) ? __fdiv_rn(bw, bh) : __fdiv_rn(bh, bw)) : 0.f;
        int   n = (int)fminf(ceilf(ratio * 8.0f), 64.0f);   // *8 exact
        float length_f = fmaxf((float)n, 2.0f);
        float fmask = non_zero ? 1.f : 0.f;
        float map_w, map_h;
        if (dir == 0) { map_w = __fdiv_rn(bw, length_f - 1.0f); map_h = __fdiv_rn(bh, 7.0f); }
        else          { map_w = __fdiv_rn(bw, 7.0f);            map_h = __fdiv_rn(bh, length_f - 1.0f); }
        int gtb = b * MAXB + bx;
        float* P = params + ((size_t)dir * 128 + gtb) * 8;
        P[0] = x1; P[1] = y1; P[2] = map_w; P[3] = map_h;
        P[4] = (float)n; P[5] = fmask; P[6] = 0.f; P[7] = 0.f;
        ((dir == 0) ? out_w : out_hh)[gtb] = (float)n;
    }
}

// ---------------------------------------------------------------------------
// Kernel 2: ROI pooling, 8 channels per thread (2x f32x4), params precomputed.
// Nontemporal stores: outputs are write-once -> keep L2 for fmap gathers.
// ---------------------------------------------------------------------------
__global__ __launch_bounds__(256) void roi_kernel(const float* __restrict__ fmap,
                                                  const float* __restrict__ params,
                                                  float* __restrict__ out_h,
                                                  float* __restrict__ out_v)
{
    int idx = blockIdx.x * 256 + threadIdx.x;    // [0, 2*OTOT)
    int dir = (idx >= OTOT) ? 1 : 0;
    int e   = idx - dir * OTOT;                  // [0, OTOT)
    int tb  = e >> 13;                           // 512 pos * 16 ch8 per box
    int within = e & 8191;
    int pos = within >> 4;                       // [0,512)
    int ch8 = within & 15;                       // channel group (8 ch)

    const f32x4* P4 = (const f32x4*)(params + ((size_t)dir * 128 + tb) * 8);
    f32x4 p0 = P4[0];
    f32x4 p1 = P4[1];
    float bz0x = p0.x, bz0y = p0.y, map_w = p0.z, map_h = p0.w;
    int   n     = (int)p1.x;
    float fmask = p1.y;

    int rr, cc; float mask;
    if (dir == 0) { rr = pos >> 6; cc = pos & 63; mask = (cc < n) ? fmask : 0.f; }
    else          { rr = pos >> 3; cc = pos & 7;  mask = (rr < n) ? fmask : 0.f; }

    int el = (tb << 16) | (pos << 7) | (ch8 << 3);
    float* outp = ((dir == 0) ? out_h : out_v) + el;

    if (mask == 0.f) {                           // masked: pooled*0 == +0
        f32x4 z = (f32x4)(0.f);
        __builtin_nontemporal_store(z, (f32x4*)outp);
        __builtin_nontemporal_store(z, (f32x4*)(outp + 4));
        return;
    }

    // separately-rounded mul then add (no FMA) — floor() is discontinuous
    float x = __fadd_rn(__fmul_rn((float)cc, map_w), bz0x);
    float y = __fadd_rn(__fmul_rn((float)rr, map_h), bz0y);

    float x0f = floorf(x), y0f = floorf(y);
    int ix0 = min(max((int)x0f,     0), 63);
    int ix1 = min(max((int)x0f + 1, 0), 63);
    int iy0 = min(max((int)y0f,     0), 63);
    int iy1 = min(max((int)y0f + 1, 0), 63);

    const float* img = fmap + ((size_t)(tb >> 5)) * (64 * 64 * 128) + (ch8 << 3);
    const float* pa = img + (iy0 * 64 + ix0) * 128;
    const float* pb = img + (iy0 * 64 + ix1) * 128;
    const float* pc = img + (iy1 * 64 + ix0) * 128;
    const float* pd = img + (iy1 * 64 + ix1) * 128;
    f32x4 Ia0 = *(const f32x4*)pa,       Ia1 = *(const f32x4*)(pa + 4);
    f32x4 Ib0 = *(const f32x4*)pb,       Ib1 = *(const f32x4*)(pb + 4);
    f32x4 Ic0 = *(const f32x4*)pc,       Ic1 = *(const f32x4*)(pc + 4);
    f32x4 Id0 = *(const f32x4*)pd,       Id1 = *(const f32x4*)(pd + 4);

    float x0v = (float)ix0, x1v = (float)ix1;
    float y0v = (float)iy0, y1v = (float)iy1;
    float wa = (x1v - x) * (y1v - y);
    float wb = (x1v - x) * (y - y0v);
    float wc = (x - x0v) * (y1v - y);
    float wd = (x - x0v) * (y - y0v);

    f32x4 o0, o1;
    o0.x = (Ia0.x * wa + Ib0.x * wb + Ic0.x * wc + Id0.x * wd) * mask;
    o0.y = (Ia0.y * wa + Ib0.y * wb + Ic0.y * wc + Id0.y * wd) * mask;
    o0.z = (Ia0.z * wa + Ib0.z * wb + Ic0.z * wc + Id0.z * wd) * mask;
    o0.w = (Ia0.w * wa + Ib0.w * wb + Ic0.w * wc + Id0.w * wd) * mask;
    o1.x = (Ia1.x * wa + Ib1.x * wb + Ic1.x * wc + Id1.x * wd) * mask;
    o1.y = (Ia1.y * wa + Ib1.y * wb + Ic1.y * wc + Id1.y * wd) * mask;
    o1.z = (Ia1.z * wa + Ib1.z * wb + Ic1.z * wc + Id1.z * wd) * mask;
    o1.w = (Ia1.w * wa + Ib1.w * wb + Ic1.w * wc + Id1.w * wd) * mask;
    __builtin_nontemporal_store(o0, (f32x4*)outp);
    __builtin_nontemporal_store(o1, (f32x4*)(outp + 4));
}

// ---------------------------------------------------------------------------
extern "C" void kernel_launch(void* const* d_in, const int* in_sizes, int n_in,
                              void* d_out, int out_size, void* d_ws, size_t ws_size,
                              hipStream_t stream) {
    const float* fmap = (const float*)d_in[0];   // (4,64,64,128)
    const float* bbox = (const float*)d_in[1];   // (4,64,64,5)
    float* out = (float*)d_out;

    // output layout (flat, return order):
    //   nms_boxes (4,32,4)        =       512
    //   h_roi     (4,32,8,64,128) = 8,388,608
    //   widths    (4,32)          =       128
    //   v_roi     (4,32,64,8,128) = 8,388,608
    //   heights   (4,32)          =       128
    float* out_nms = out;
    float* out_h   = out + 512;
    float* out_w   = out_h + ROI_N;
    float* out_v   = out_w + 128;
    float* out_hh  = out_v + ROI_N;

    float* params = (float*)d_ws;   // [2][128][8] floats = 8 KB

    nms_kernel<<<NB, 256, 0, stream>>>(bbox, out_nms, params, out_w, out_hh);
    roi_kernel<<<(2 * OTOT) / 256, 256, 0, stream>>>(fmap, params, out_h, out_v);
}

// Round 9
// 191.365 us; speedup vs baseline: 1.0671x; 1.0671x over previous
//
#include <hip/hip_runtime.h>
#include <hip/hip_bf16.h>
#include <math.h>

// Exact numpy rounding everywhere: no FMA contraction in this file.
#pragma clang fp contract(off)

#define NPIX 4096      // 64*64
#define MAXB 32
#define NB   4
#define ROI_N 8388608          // 4*32*8*64*128 elements per roi tensor

typedef float f32x4 __attribute__((ext_vector_type(4)));

// ---------------------------------------------------------------------------
// Kernel 1 (R6-proven): per-batch score/box reconstruct + serial NMS, one
// block per batch. Per iteration: ONE fused register pass (suppress-vs-prev-
// winner + argmax), 6-step butterfly, ONE barrier (double-buffered reduce
// slots), broadcast winner-box read. Candidates live in registers.
// ---------------------------------------------------------------------------
__global__ __launch_bounds__(256) void nms_kernel(const float* __restrict__ bbox,
                                                  float* __restrict__ out_nms,
                                                  float* __restrict__ params,
                                                  float* __restrict__ out_w,
                                                  float* __restrict__ out_hh)
{
    const int b = blockIdx.x;
    const int t = threadIdx.x;

    __shared__ float s_box[NPIX][4];     // 64 KB, winner broadcast lookup
    __shared__ float s_sel[MAXB][4];     // selected (keep-applied) boxes
    __shared__ float s_red[2][4][2];     // [buf][wave][score, idx-as-float]

    float rs[16], rx1[16], ry1[16], rx2[16], ry2[16], rar[16];

    const float* src = bbox + (size_t)b * NPIX * 5;

    #pragma unroll
    for (int i = 0; i < 16; ++i) {
        int p = i * 256 + t;
        int y = p >> 6, x = p & 63;
        float c0 = src[p * 5 + 0];
        float c1 = src[p * 5 + 1];
        float c2 = src[p * 5 + 2];
        float c3 = src[p * 5 + 3];
        float c4 = src[p * 5 + 4];
        float sc = 1.0f / (1.0f + expf(-c0));   // keep formulation byte-identical
        float x1 = 8.0f * ((float)x - c1);
        float y1 = 8.0f * ((float)y - c2);
        float x2 = 8.0f * ((float)x + c3);
        float y2 = 8.0f * ((float)y + c4);
        rs[i] = sc;
        rx1[i] = x1; ry1[i] = y1; rx2[i] = x2; ry2[i] = y2;
        rar[i] = (x2 - x1) * (y2 - y1);
        s_box[p][0] = x1; s_box[p][1] = y1; s_box[p][2] = x2; s_box[p][3] = y2;
    }
    __syncthreads();

    unsigned valid = 0xFFFFu;            // bit i <-> candidate p = i*256 + t
    // dummy previous winner: IoU vs it is exactly 0 for any real box
    float wx1 = -1e30f, wy1 = -1e30f, wx2 = -1e30f, wy2 = -1e30f, warea = 0.f;

    for (int it = 0; it < MAXB; ++it) {
        // ---- fused: suppress vs previous winner + branchless argmax ----
        float best = -INFINITY;
        int   bidx = 0x7FFFFFFF;
        #pragma unroll
        for (int i = 0; i < 16; ++i) {
            float iw = fmaxf(fminf(rx2[i], wx2) - fmaxf(rx1[i], wx1), 0.f);
            float ih = fmaxf(fminf(ry2[i], wy2) - fmaxf(ry1[i], wy1), 0.f);
            float inter = iw * ih;
            float iou = __fdiv_rn(inter, rar[i] + warea - inter + 1e-9f);
            valid &= ~(((iou > 0.5f) ? 1u : 0u) << i);
            float vv = ((valid >> i) & 1u) ? rs[i] : -INFINITY;
            bool take = vv > best;       // strict > keeps lowest p (i ascending)
            bidx = take ? (i * 256 + t) : bidx;
            best = take ? vv : best;
        }
        // ---- wave butterfly reduce ----
        #pragma unroll
        for (int off = 32; off; off >>= 1) {
            float ov = __shfl_xor(best, off);
            int   oi = __shfl_xor(bidx, off);
            bool take = (ov > best) || (ov == best && oi < bidx);
            best = take ? ov : best;
            bidx = take ? oi : bidx;
        }
        int buf = it & 1;
        if ((t & 63) == 0) {
            s_red[buf][t >> 6][0] = best;
            s_red[buf][t >> 6][1] = __int_as_float(bidx);
        }
        __syncthreads();                 // the ONLY barrier in the iteration
        best = s_red[buf][0][0]; bidx = __float_as_int(s_red[buf][0][1]);
        #pragma unroll
        for (int wv = 1; wv < 4; ++wv) {
            float ov = s_red[buf][wv][0];
            int   oi = __float_as_int(s_red[buf][wv][1]);
            bool take = (ov > best) || (ov == best && oi < bidx);
            best = take ? ov : best;
            bidx = take ? oi : bidx;
        }

        // winner box broadcast (clamped; if best==-inf no valid bits exist,
        // so a garbage winner suppresses nothing and output is zeroed anyway)
        int jj = min(bidx, NPIX - 1);
        wx1 = s_box[jj][0]; wy1 = s_box[jj][1];
        wx2 = s_box[jj][2]; wy2 = s_box[jj][3];
        warea = (wx2 - wx1) * (wy2 - wy1);   // same formula as rar -> bit-exact

        if (t == 0) {
            bool keep = (best >= 0.3f);      // -inf fails this too
            float o0 = keep ? wx1 : 0.f, o1 = keep ? wy1 : 0.f;
            float o2 = keep ? wx2 : 0.f, o3 = keep ? wy2 : 0.f;
            float* o = out_nms + ((size_t)b * MAXB + it) * 4;
            o[0] = o0; o[1] = o1; o[2] = o2; o[3] = o3;
            s_sel[it][0] = o0; s_sel[it][1] = o1;
            s_sel[it][2] = o2; s_sel[it][3] = o3;
        }
    }
    __syncthreads();                      // publish s_sel to epilogue

    // ---- epilogue: per-(dir, box) ROI params, once per box ----
    if (t < 64) {
        int dir = t >> 5, bx = t & 31;
        float x1 = s_sel[bx][0] * 0.125f, y1 = s_sel[bx][1] * 0.125f;  // exact /8
        float x2 = s_sel[bx][2] * 0.125f, y2 = s_sel[bx][3] * 0.125f;
        float w = x2 - x1, h = y2 - y1;
        bool is_dir = (dir == 0) ? (w >= h) : (w < h);
        if (!is_dir) { x1 = 0.f; y1 = 0.f; x2 = 0.f; y2 = 0.f; }
        w = x2 - x1; h = y2 - y1;
        bool  non_zero = (w >= 0.1f) || (h >= 0.1f);
        float bw = (w <= 0.f) ? 1e-4f : w;
        float bh = (h <= 0.f) ? 1e-4f : h;
        float ratio = non_zero ? ((dir == 0) ? __fdiv_rn(bw, bh) : __fdiv_rn(bh, bw)) : 0.f;
        int   n = (int)fminf(ceilf(ratio * 8.0f), 64.0f);   // *8 exact
        float length_f = fmaxf((float)n, 2.0f);
        float fmask = non_zero ? 1.f : 0.f;
        float map_w, map_h;
        if (dir == 0) { map_w = __fdiv_rn(bw, length_f - 1.0f); map_h = __fdiv_rn(bh, 7.0f); }
        else          { map_w = __fdiv_rn(bw, 7.0f);            map_h = __fdiv_rn(bh, length_f - 1.0f); }
        int gtb = b * MAXB + bx;
        float* P = params + ((size_t)dir * 128 + gtb) * 8;
        P[0] = x1; P[1] = y1; P[2] = map_w; P[3] = map_h;
        P[4] = (float)n; P[5] = fmask; P[6] = 0.f; P[7] = 0.f;
        ((dir == 0) ? out_w : out_hh)[gtb] = (float)n;
    }
}

// ---------------------------------------------------------------------------
// Kernel 2: ROI pooling, 16 channels per thread (4x f32x4). (dir, box) are
// derived from blockIdx only -> wave-uniform -> params load via scalar path.
// Nontemporal stores: outputs are write-once, keep L2 for fmap gathers.
// Grid: 4096 blocks x 256 threads; 16 blocks per (dir,box).
// ---------------------------------------------------------------------------
__global__ __launch_bounds__(256) void roi_kernel(const float* __restrict__ fmap,
                                                  const float* __restrict__ params,
                                                  float* __restrict__ out_h,
                                                  float* __restrict__ out_v)
{
    int blk = blockIdx.x;                 // [0, 4096)
    int dir = (blk >= 2048) ? 1 : 0;      // uniform per block
    int bb  = blk - dir * 2048;           // [0, 2048)
    int tb  = bb >> 4;                    // box index [0,128), uniform per block
    int sub = bb & 15;                    // slice within box

    // wave-uniform address -> scalar loads
    const float* P = params + ((size_t)(dir * 128 + tb)) * 8;
    float bz0x = P[0], bz0y = P[1], map_w = P[2], map_h = P[3];
    int   n     = (int)P[4];
    float fmask = P[5];

    int item = (sub << 8) | threadIdx.x;  // [0, 4096) per box: 512 pos x 8 ch16
    int pos  = item >> 3;                 // [0,512)
    int ch16 = item & 7;                  // 16-channel group

    int rr, cc; float mask;
    if (dir == 0) { rr = pos >> 6; cc = pos & 63; mask = (cc < n) ? fmask : 0.f; }
    else          { rr = pos >> 3; cc = pos & 7;  mask = (rr < n) ? fmask : 0.f; }

    int el = (tb << 16) | (pos << 7) | (ch16 << 4);
    float* outp = ((dir == 0) ? out_h : out_v) + el;

    if (mask == 0.f) {                    // masked: pooled*0 == +0
        f32x4 z = (f32x4)(0.f);
        #pragma unroll
        for (int k = 0; k < 4; ++k)
            __builtin_nontemporal_store(z, (f32x4*)(outp + 4 * k));
        return;
    }

    // separately-rounded mul then add (no FMA) — floor() is discontinuous
    float x = __fadd_rn(__fmul_rn((float)cc, map_w), bz0x);
    float y = __fadd_rn(__fmul_rn((float)rr, map_h), bz0y);

    float x0f = floorf(x), y0f = floorf(y);
    int ix0 = min(max((int)x0f,     0), 63);
    int ix1 = min(max((int)x0f + 1, 0), 63);
    int iy0 = min(max((int)y0f,     0), 63);
    int iy1 = min(max((int)y0f + 1, 0), 63);

    const float* img = fmap + ((size_t)(tb >> 5)) * (64 * 64 * 128) + (ch16 << 4);
    const float* pa = img + (iy0 * 64 + ix0) * 128;
    const float* pb = img + (iy0 * 64 + ix1) * 128;
    const float* pc = img + (iy1 * 64 + ix0) * 128;
    const float* pd = img + (iy1 * 64 + ix1) * 128;

    float x0v = (float)ix0, x1v = (float)ix1;
    float y0v = (float)iy0, y1v = (float)iy1;
    float wa = (x1v - x) * (y1v - y);
    float wb = (x1v - x) * (y - y0v);
    float wc = (x - x0v) * (y1v - y);
    float wd = (x - x0v) * (y - y0v);

    #pragma unroll
    for (int k = 0; k < 4; ++k) {
        f32x4 Ia = *(const f32x4*)(pa + 4 * k);
        f32x4 Ib = *(const f32x4*)(pb + 4 * k);
        f32x4 Ic = *(const f32x4*)(pc + 4 * k);
        f32x4 Id = *(const f32x4*)(pd + 4 * k);
        f32x4 o;
        o.x = (Ia.x * wa + Ib.x * wb + Ic.x * wc + Id.x * wd) * mask;
        o.y = (Ia.y * wa + Ib.y * wb + Ic.y * wc + Id.y * wd) * mask;
        o.z = (Ia.z * wa + Ib.z * wb + Ic.z * wc + Id.z * wd) * mask;
        o.w = (Ia.w * wa + Ib.w * wb + Ic.w * wc + Id.w * wd) * mask;
        __builtin_nontemporal_store(o, (f32x4*)(outp + 4 * k));
    }
}

// ---------------------------------------------------------------------------
extern "C" void kernel_launch(void* const* d_in, const int* in_sizes, int n_in,
                              void* d_out, int out_size, void* d_ws, size_t ws_size,
                              hipStream_t stream) {
    const float* fmap = (const float*)d_in[0];   // (4,64,64,128)
    const float* bbox = (const float*)d_in[1];   // (4,64,64,5)
    float* out = (float*)d_out;

    // output layout (flat, return order):
    //   nms_boxes (4,32,4)        =       512
    //   h_roi     (4,32,8,64,128) = 8,388,608
    //   widths    (4,32)          =       128
    //   v_roi     (4,32,64,8,128) = 8,388,608
    //   heights   (4,32)          =       128
    float* out_nms = out;
    float* out_h   = out + 512;
    float* out_w   = out_h + ROI_N;
    float* out_v   = out_w + 128;
    float* out_hh  = out_v + ROI_N;

    float* params = (float*)d_ws;   // [2][128][8] floats = 8 KB

    nms_kernel<<<NB, 256, 0, stream>>>(bbox, out_nms, params, out_w, out_hh);
    roi_kernel<<<4096, 256, 0, stream>>>(fmap, params, out_h, out_v);
}

// Round 11
// 141.922 us; speedup vs baseline: 1.4389x; 1.3484x over previous
//
#include <hip/hip_runtime.h>
#include <hip/hip_bf16.h>
#include <math.h>

// Exact numpy rounding everywhere: no FMA contraction in this file.
#pragma clang fp contract(off)

#define NPIX 4096      // 64*64
#define MAXB 32
#define NB   4
#define ROI_N 8388608          // 4*32*8*64*128 elements per roi tensor

typedef float f32x4 __attribute__((ext_vector_type(4)));

// ---------------------------------------------------------------------------
// Kernel 1: per-batch score/box reconstruct + serial NMS, one block per
// batch, 512 threads (8 waves, 8 candidates per lane). Per iteration: ONE
// fused register pass (suppress-vs-prev-winner + argmax), 6-step butterfly,
// ONE barrier (double-buffered reduce slots), broadcast winner-box read.
// ---------------------------------------------------------------------------
__global__ __launch_bounds__(512) void nms_kernel(const float* __restrict__ bbox,
                                                  float* __restrict__ out_nms,
                                                  float* __restrict__ params,
                                                  float* __restrict__ out_w,
                                                  float* __restrict__ out_hh)
{
    const int b = blockIdx.x;
    const int t = threadIdx.x;           // [0,512)

    __shared__ float s_box[NPIX][4];     // 64 KB, winner broadcast lookup
    __shared__ float s_sel[MAXB][4];     // selected (keep-applied) boxes
    __shared__ float s_red[2][8][2];     // [buf][wave][score, idx-as-float]

    float rs[8], rx1[8], ry1[8], rx2[8], ry2[8], rar[8];

    const float* src = bbox + (size_t)b * NPIX * 5;

    #pragma unroll
    for (int i = 0; i < 8; ++i) {
        int p = i * 512 + t;
        int y = p >> 6, x = p & 63;
        float c0 = src[p * 5 + 0];
        float c1 = src[p * 5 + 1];
        float c2 = src[p * 5 + 2];
        float c3 = src[p * 5 + 3];
        float c4 = src[p * 5 + 4];
        float sc = 1.0f / (1.0f + expf(-c0));   // keep formulation byte-identical
        float x1 = 8.0f * ((float)x - c1);
        float y1 = 8.0f * ((float)y - c2);
        float x2 = 8.0f * ((float)x + c3);
        float y2 = 8.0f * ((float)y + c4);
        rs[i] = sc;
        rx1[i] = x1; ry1[i] = y1; rx2[i] = x2; ry2[i] = y2;
        rar[i] = (x2 - x1) * (y2 - y1);
        s_box[p][0] = x1; s_box[p][1] = y1; s_box[p][2] = x2; s_box[p][3] = y2;
    }
    __syncthreads();

    unsigned valid = 0xFFu;              // bit i <-> candidate p = i*512 + t
    // dummy previous winner: IoU vs it is exactly 0 for any real box
    float wx1 = -1e30f, wy1 = -1e30f, wx2 = -1e30f, wy2 = -1e30f, warea = 0.f;

    for (int it = 0; it < MAXB; ++it) {
        // ---- fused: suppress vs previous winner + branchless argmax ----
        float best = -INFINITY;
        int   bidx = 0x7FFFFFFF;
        #pragma unroll
        for (int i = 0; i < 8; ++i) {
            float iw = fmaxf(fminf(rx2[i], wx2) - fmaxf(rx1[i], wx1), 0.f);
            float ih = fmaxf(fminf(ry2[i], wy2) - fmaxf(ry1[i], wy1), 0.f);
            float inter = iw * ih;
            float iou = __fdiv_rn(inter, rar[i] + warea - inter + 1e-9f);
            valid &= ~(((iou > 0.5f) ? 1u : 0u) << i);
            float vv = ((valid >> i) & 1u) ? rs[i] : -INFINITY;
            bool take = vv > best;       // strict > keeps lowest p (i ascending)
            bidx = take ? (i * 512 + t) : bidx;
            best = take ? vv : best;
        }
        // ---- wave butterfly reduce ----
        #pragma unroll
        for (int off = 32; off; off >>= 1) {
            float ov = __shfl_xor(best, off);
            int   oi = __shfl_xor(bidx, off);
            bool take = (ov > best) || (ov == best && oi < bidx);
            best = take ? ov : best;
            bidx = take ? oi : bidx;
        }
        int buf = it & 1;
        if ((t & 63) == 0) {
            s_red[buf][t >> 6][0] = best;
            s_red[buf][t >> 6][1] = __int_as_float(bidx);
        }
        __syncthreads();                 // the ONLY barrier in the iteration
        best = s_red[buf][0][0]; bidx = __float_as_int(s_red[buf][0][1]);
        #pragma unroll
        for (int wv = 1; wv < 8; ++wv) {
            float ov = s_red[buf][wv][0];
            int   oi = __float_as_int(s_red[buf][wv][1]);
            bool take = (ov > best) || (ov == best && oi < bidx);
            best = take ? ov : best;
            bidx = take ? oi : bidx;
        }

        // winner box broadcast (clamped; if best==-inf no valid bits exist,
        // so a garbage winner suppresses nothing and output is zeroed anyway)
        int jj = min(bidx, NPIX - 1);
        wx1 = s_box[jj][0]; wy1 = s_box[jj][1];
        wx2 = s_box[jj][2]; wy2 = s_box[jj][3];
        warea = (wx2 - wx1) * (wy2 - wy1);   // same formula as rar -> bit-exact

        if (t == 0) {
            bool keep = (best >= 0.3f);      // -inf fails this too
            float o0 = keep ? wx1 : 0.f, o1 = keep ? wy1 : 0.f;
            float o2 = keep ? wx2 : 0.f, o3 = keep ? wy2 : 0.f;
            float* o = out_nms + ((size_t)b * MAXB + it) * 4;
            o[0] = o0; o[1] = o1; o[2] = o2; o[3] = o3;
            s_sel[it][0] = o0; s_sel[it][1] = o1;
            s_sel[it][2] = o2; s_sel[it][3] = o3;
        }
    }
    __syncthreads();                      // publish s_sel to epilogue

    // ---- epilogue: per-(dir, box) ROI params, once per box ----
    if (t < 64) {
        int dir = t >> 5, bx = t & 31;
        float x1 = s_sel[bx][0] * 0.125f, y1 = s_sel[bx][1] * 0.125f;  // exact /8
        float x2 = s_sel[bx][2] * 0.125f, y2 = s_sel[bx][3] * 0.125f;
        float w = x2 - x1, h = y2 - y1;
        bool is_dir = (dir == 0) ? (w >= h) : (w < h);
        if (!is_dir) { x1 = 0.f; y1 = 0.f; x2 = 0.f; y2 = 0.f; }
        w = x2 - x1; h = y2 - y1;
        bool  non_zero = (w >= 0.1f) || (h >= 0.1f);
        float bw = (w <= 0.f) ? 1e-4f : w;
        float bh = (h <= 0.f) ? 1e-4f : h;
        float ratio = non_zero ? ((dir == 0) ? __fdiv_rn(bw, bh) : __fdiv_rn(bh, bw)) : 0.f;
        int   n = (int)fminf(ceilf(ratio * 8.0f), 64.0f);   // *8 exact
        float length_f = fmaxf((float)n, 2.0f);
        float fmask = non_zero ? 1.f : 0.f;
        float map_w, map_h;
        if (dir == 0) { map_w = __fdiv_rn(bw, length_f - 1.0f); map_h = __fdiv_rn(bh, 7.0f); }
        else          { map_w = __fdiv_rn(bw, 7.0f);            map_h = __fdiv_rn(bh, length_f - 1.0f); }
        int gtb = b * MAXB + bx;
        float* P = params + ((size_t)dir * 128 + gtb) * 8;
        P[0] = x1; P[1] = y1; P[2] = map_w; P[3] = map_h;
        P[4] = (float)n; P[5] = fmask; P[6] = 0.f; P[7] = 0.f;
        ((dir == 0) ? out_w : out_hh)[gtb] = (float)n;
    }
}

// ---------------------------------------------------------------------------
// Kernel 2: ROI pooling — R8-proven 8-channels-per-thread mapping (2x f32x4
// nontemporal stores, 32B/thread, lane-stride 32B -> combines cleanly), with
// (dir, box) derived from blockIdx only -> scalar param loads.
// Grid: 8192 blocks x 256 threads; 32 blocks per (dir,box).
// ---------------------------------------------------------------------------
__global__ __launch_bounds__(256) void roi_kernel(const float* __restrict__ fmap,
                                                  const float* __restrict__ params,
                                                  float* __restrict__ out_h,
                                                  float* __restrict__ out_v)
{
    int blk = blockIdx.x;                 // [0, 8192)
    int dir = (blk >= 4096) ? 1 : 0;      // uniform per block
    int bb  = blk - dir * 4096;           // [0, 4096)
    int tb  = bb >> 5;                    // box index [0,128), uniform per block
    int sub = bb & 31;                    // slice within box

    // wave-uniform address -> scalar loads
    const float* P = params + ((size_t)(dir * 128 + tb)) * 8;
    float bz0x = P[0], bz0y = P[1], map_w = P[2], map_h = P[3];
    int   n     = (int)P[4];
    float fmask = P[5];

    int item = (sub << 8) | threadIdx.x;  // [0, 8192) per box: 512 pos x 16 ch8
    int pos  = item >> 4;                 // [0,512)
    int ch8  = item & 15;                 // 8-channel group

    int rr, cc; float mask;
    if (dir == 0) { rr = pos >> 6; cc = pos & 63; mask = (cc < n) ? fmask : 0.f; }
    else          { rr = pos >> 3; cc = pos & 7;  mask = (rr < n) ? fmask : 0.f; }

    int el = (tb << 16) | (pos << 7) | (ch8 << 3);
    float* outp = ((dir == 0) ? out_h : out_v) + el;

    if (mask == 0.f) {                    // masked: pooled*0 == +0
        f32x4 z = (f32x4)(0.f);
        __builtin_nontemporal_store(z, (f32x4*)outp);
        __builtin_nontemporal_store(z, (f32x4*)(outp + 4));
        return;
    }

    // separately-rounded mul then add (no FMA) — floor() is discontinuous
    float x = __fadd_rn(__fmul_rn((float)cc, map_w), bz0x);
    float y = __fadd_rn(__fmul_rn((float)rr, map_h), bz0y);

    float x0f = floorf(x), y0f = floorf(y);
    int ix0 = min(max((int)x0f,     0), 63);
    int ix1 = min(max((int)x0f + 1, 0), 63);
    int iy0 = min(max((int)y0f,     0), 63);
    int iy1 = min(max((int)y0f + 1, 0), 63);

    const float* img = fmap + ((size_t)(tb >> 5)) * (64 * 64 * 128) + (ch8 << 3);
    const float* pa = img + (iy0 * 64 + ix0) * 128;
    const float* pb = img + (iy0 * 64 + ix1) * 128;
    const float* pc = img + (iy1 * 64 + ix0) * 128;
    const float* pd = img + (iy1 * 64 + ix1) * 128;
    f32x4 Ia0 = *(const f32x4*)pa,       Ia1 = *(const f32x4*)(pa + 4);
    f32x4 Ib0 = *(const f32x4*)pb,       Ib1 = *(const f32x4*)(pb + 4);
    f32x4 Ic0 = *(const f32x4*)pc,       Ic1 = *(const f32x4*)(pc + 4);
    f32x4 Id0 = *(const f32x4*)pd,       Id1 = *(const f32x4*)(pd + 4);

    float x0v = (float)ix0, x1v = (float)ix1;
    float y0v = (float)iy0, y1v = (float)iy1;
    float wa = (x1v - x) * (y1v - y);
    float wb = (x1v - x) * (y - y0v);
    float wc = (x - x0v) * (y1v - y);
    float wd = (x - x0v) * (y - y0v);

    f32x4 o0, o1;
    o0.x = (Ia0.x * wa + Ib0.x * wb + Ic0.x * wc + Id0.x * wd) * mask;
    o0.y = (Ia0.y * wa + Ib0.y * wb + Ic0.y * wc + Id0.y * wd) * mask;
    o0.z = (Ia0.z * wa + Ib0.z * wb + Ic0.z * wc + Id0.z * wd) * mask;
    o0.w = (Ia0.w * wa + Ib0.w * wb + Ic0.w * wc + Id0.w * wd) * mask;
    o1.x = (Ia1.x * wa + Ib1.x * wb + Ic1.x * wc + Id1.x * wd) * mask;
    o1.y = (Ia1.y * wa + Ib1.y * wb + Ic1.y * wc + Id1.y * wd) * mask;
    o1.z = (Ia1.z * wa + Ib1.z * wb + Ic1.z * wc + Id1.z * wd) * mask;
    o1.w = (Ia1.w * wa + Ib1.w * wb + Ic1.w * wc + Id1.w * wd) * mask;
    __builtin_nontemporal_store(o0, (f32x4*)outp);
    __builtin_nontemporal_store(o1, (f32x4*)(outp + 4));
}

// ---------------------------------------------------------------------------
extern "C" void kernel_launch(void* const* d_in, const int* in_sizes, int n_in,
                              void* d_out, int out_size, void* d_ws, size_t ws_size,
                              hipStream_t stream) {
    const float* fmap = (const float*)d_in[0];   // (4,64,64,128)
    const float* bbox = (const float*)d_in[1];   // (4,64,64,5)
    float* out = (float*)d_out;

    // output layout (flat, return order):
    //   nms_boxes (4,32,4)        =       512
    //   h_roi     (4,32,8,64,128) = 8,388,608
    //   widths    (4,32)          =       128
    //   v_roi     (4,32,64,8,128) = 8,388,608
    //   heights   (4,32)          =       128
    float* out_nms = out;
    float* out_h   = out + 512;
    float* out_w   = out_h + ROI_N;
    float* out_v   = out_w + 128;
    float* out_hh  = out_v + ROI_N;

    float* params = (float*)d_ws;   // [2][128][8] floats = 8 KB

    nms_kernel<<<NB, 512, 0, stream>>>(bbox, out_nms, params, out_w, out_hh);
    roi_kernel<<<8192, 256, 0, stream>>>(fmap, params, out_h, out_v);
}

// Round 12
// 139.275 us; speedup vs baseline: 1.4662x; 1.0190x over previous
//
#include <hip/hip_runtime.h>
#include <hip/hip_bf16.h>
#include <math.h>

// Exact numpy rounding everywhere: no FMA contraction in this file.
#pragma clang fp contract(off)

#define NPIX 4096      // 64*64
#define MAXB 32
#define NB   4
#define ROI_N 8388608          // 4*32*8*64*128 elements per roi tensor

typedef float f32x4 __attribute__((ext_vector_type(4)));

// ---------------------------------------------------------------------------
// Kernel 1: per-batch score/box reconstruct + serial NMS, one block per
// batch, 256 threads (4 waves, 16 candidates per lane). Per iteration:
// fused register pass (suppress-vs-prev-winner + argmax) with EXACT
// multiply-compare (no divide), 6-step butterfly, ONE barrier, and the
// winner BOX carried through the reduce slots (no dependent post-reduce
// s_box read on the critical path).
// ---------------------------------------------------------------------------
__global__ __launch_bounds__(256) void nms_kernel(const float* __restrict__ bbox,
                                                  float* __restrict__ out_nms,
                                                  float* __restrict__ params,
                                                  float* __restrict__ out_w,
                                                  float* __restrict__ out_hh)
{
    const int b = blockIdx.x;
    const int t = threadIdx.x;           // [0,256)

    __shared__ float s_box[NPIX][4];     // 64 KB, wave-leader box lookup
    __shared__ float s_sel[MAXB][4];     // selected (keep-applied) boxes
    __shared__ float s_red[2][4][8];     // [buf][wave][best,idx,x1,y1,x2,y2,area,pad]

    float rs[16], rx1[16], ry1[16], rx2[16], ry2[16], rar[16];

    const float* src = bbox + (size_t)b * NPIX * 5;

    #pragma unroll
    for (int i = 0; i < 16; ++i) {
        int p = i * 256 + t;
        int y = p >> 6, x = p & 63;
        float c0 = src[p * 5 + 0];
        float c1 = src[p * 5 + 1];
        float c2 = src[p * 5 + 2];
        float c3 = src[p * 5 + 3];
        float c4 = src[p * 5 + 4];
        float sc = 1.0f / (1.0f + expf(-c0));   // keep formulation byte-identical
        float x1 = 8.0f * ((float)x - c1);
        float y1 = 8.0f * ((float)y - c2);
        float x2 = 8.0f * ((float)x + c3);
        float y2 = 8.0f * ((float)y + c4);
        rs[i] = sc;
        rx1[i] = x1; ry1[i] = y1; rx2[i] = x2; ry2[i] = y2;
        rar[i] = (x2 - x1) * (y2 - y1);
        s_box[p][0] = x1; s_box[p][1] = y1; s_box[p][2] = x2; s_box[p][3] = y2;
    }
    __syncthreads();

    unsigned valid = 0xFFFFu;            // bit i <-> candidate p = i*256 + t
    // dummy previous winner: IoU vs it is exactly 0 for any real box
    float wx1 = -1e30f, wy1 = -1e30f, wx2 = -1e30f, wy2 = -1e30f, warea = 0.f;

    for (int it = 0; it < MAXB; ++it) {
        // ---- fused: suppress vs previous winner + branchless argmax ----
        // iou > 0.5  <=>  inter > 0.5*denom  (0.5*denom exact: pow2 multiply)
        float best = -INFINITY;
        int   bidx = 0x7FFFFFFF;
        #pragma unroll
        for (int i = 0; i < 16; ++i) {
            float iw = fmaxf(fminf(rx2[i], wx2) - fmaxf(rx1[i], wx1), 0.f);
            float ih = fmaxf(fminf(ry2[i], wy2) - fmaxf(ry1[i], wy1), 0.f);
            float inter = iw * ih;
            float denom = rar[i] + warea - inter + 1e-9f;   // ref rounding order
            valid &= ~(((inter > 0.5f * denom) ? 1u : 0u) << i);
            float vv = ((valid >> i) & 1u) ? rs[i] : -INFINITY;
            bool take = vv > best;       // strict > keeps lowest p (i ascending)
            bidx = take ? (i * 256 + t) : bidx;
            best = take ? vv : best;
        }
        // ---- wave butterfly reduce ----
        #pragma unroll
        for (int off = 32; off; off >>= 1) {
            float ov = __shfl_xor(best, off);
            int   oi = __shfl_xor(bidx, off);
            bool take = (ov > best) || (ov == best && oi < bidx);
            best = take ? ov : best;
            bidx = take ? oi : bidx;
        }
        int buf = it & 1;
        if ((t & 63) == 0) {
            // leader fetches its wave-max's box BEFORE the barrier (latency
            // hidden under other waves' arrival) and publishes box+area.
            int jj = min(bidx, NPIX - 1);    // clamp (garbage only if best=-inf)
            float bx1 = s_box[jj][0], by1 = s_box[jj][1];
            float bx2 = s_box[jj][2], by2 = s_box[jj][3];
            float* slot = &s_red[buf][t >> 6][0];
            slot[0] = best;
            slot[1] = __int_as_float(bidx);
            slot[2] = bx1; slot[3] = by1; slot[4] = bx2; slot[5] = by2;
            slot[6] = (bx2 - bx1) * (by2 - by1);   // same formula as rar
        }
        __syncthreads();                 // the ONLY barrier in the iteration

        // ---- cross-wave reduce, box carried along (broadcast LDS reads) ----
        best = s_red[buf][0][0]; bidx = __float_as_int(s_red[buf][0][1]);
        wx1 = s_red[buf][0][2]; wy1 = s_red[buf][0][3];
        wx2 = s_red[buf][0][4]; wy2 = s_red[buf][0][5];
        warea = s_red[buf][0][6];
        #pragma unroll
        for (int wv = 1; wv < 4; ++wv) {
            float ov = s_red[buf][wv][0];
            int   oi = __float_as_int(s_red[buf][wv][1]);
            bool take = (ov > best) || (ov == best && oi < bidx);
            best = take ? ov : best;
            bidx = take ? oi : bidx;
            wx1 = take ? s_red[buf][wv][2] : wx1;
            wy1 = take ? s_red[buf][wv][3] : wy1;
            wx2 = take ? s_red[buf][wv][4] : wx2;
            wy2 = take ? s_red[buf][wv][5] : wy2;
            warea = take ? s_red[buf][wv][6] : warea;
        }

        bool ok = (best > -INFINITY);
        if (!ok) {                       // no candidates: neutralize winner
            wx1 = -1e30f; wy1 = -1e30f; wx2 = -1e30f; wy2 = -1e30f; warea = 0.f;
        }

        if (t == 0) {
            bool keep = (best >= 0.3f);  // -inf fails this too
            float o0 = keep ? wx1 : 0.f, o1 = keep ? wy1 : 0.f;
            float o2 = keep ? wx2 : 0.f, o3 = keep ? wy2 : 0.f;
            float* o = out_nms + ((size_t)b * MAXB + it) * 4;
            o[0] = o0; o[1] = o1; o[2] = o2; o[3] = o3;
            s_sel[it][0] = o0; s_sel[it][1] = o1;
            s_sel[it][2] = o2; s_sel[it][3] = o3;
        }
    }
    __syncthreads();                      // publish s_sel to epilogue

    // ---- epilogue: per-(dir, box) ROI params, once per box ----
    if (t < 64) {
        int dir = t >> 5, bx = t & 31;
        float x1 = s_sel[bx][0] * 0.125f, y1 = s_sel[bx][1] * 0.125f;  // exact /8
        float x2 = s_sel[bx][2] * 0.125f, y2 = s_sel[bx][3] * 0.125f;
        float w = x2 - x1, h = y2 - y1;
        bool is_dir = (dir == 0) ? (w >= h) : (w < h);
        if (!is_dir) { x1 = 0.f; y1 = 0.f; x2 = 0.f; y2 = 0.f; }
        w = x2 - x1; h = y2 - y1;
        bool  non_zero = (w >= 0.1f) || (h >= 0.1f);
        float bw = (w <= 0.f) ? 1e-4f : w;
        float bh = (h <= 0.f) ? 1e-4f : h;
        float ratio = non_zero ? ((dir == 0) ? __fdiv_rn(bw, bh) : __fdiv_rn(bh, bw)) : 0.f;
        int   n = (int)fminf(ceilf(ratio * 8.0f), 64.0f);   // *8 exact
        float length_f = fmaxf((float)n, 2.0f);
        float fmask = non_zero ? 1.f : 0.f;
        float map_w, map_h;
        if (dir == 0) { map_w = __fdiv_rn(bw, length_f - 1.0f); map_h = __fdiv_rn(bh, 7.0f); }
        else          { map_w = __fdiv_rn(bw, 7.0f);            map_h = __fdiv_rn(bh, length_f - 1.0f); }
        int gtb = b * MAXB + bx;
        float* P = params + ((size_t)dir * 128 + gtb) * 8;
        P[0] = x1; P[1] = y1; P[2] = map_w; P[3] = map_h;
        P[4] = (float)n; P[5] = fmask; P[6] = 0.f; P[7] = 0.f;
        ((dir == 0) ? out_w : out_hh)[gtb] = (float)n;
    }
}

// ---------------------------------------------------------------------------
// Kernel 2: ROI pooling — 8-channels-per-thread mapping (2x f32x4
// nontemporal stores, 32B/thread -> combines cleanly), (dir, box) derived
// from blockIdx only -> scalar param loads.
// Grid: 8192 blocks x 256 threads; 32 blocks per (dir,box).
// ---------------------------------------------------------------------------
__global__ __launch_bounds__(256) void roi_kernel(const float* __restrict__ fmap,
                                                  const float* __restrict__ params,
                                                  float* __restrict__ out_h,
                                                  float* __restrict__ out_v)
{
    int blk = blockIdx.x;                 // [0, 8192)
    int dir = (blk >= 4096) ? 1 : 0;      // uniform per block
    int bb  = blk - dir * 4096;           // [0, 4096)
    int tb  = bb >> 5;                    // box index [0,128), uniform per block
    int sub = bb & 31;                    // slice within box

    // wave-uniform address -> scalar loads
    const float* P = params + ((size_t)(dir * 128 + tb)) * 8;
    float bz0x = P[0], bz0y = P[1], map_w = P[2], map_h = P[3];
    int   n     = (int)P[4];
    float fmask = P[5];

    int item = (sub << 8) | threadIdx.x;  // [0, 8192) per box: 512 pos x 16 ch8
    int pos  = item >> 4;                 // [0,512)
    int ch8  = item & 15;                 // 8-channel group

    int rr, cc; float mask;
    if (dir == 0) { rr = pos >> 6; cc = pos & 63; mask = (cc < n) ? fmask : 0.f; }
    else          { rr = pos >> 3; cc = pos & 7;  mask = (rr < n) ? fmask : 0.f; }

    int el = (tb << 16) | (pos << 7) | (ch8 << 3);
    float* outp = ((dir == 0) ? out_h : out_v) + el;

    if (mask == 0.f) {                    // masked: pooled*0 == +0
        f32x4 z = (f32x4)(0.f);
        __builtin_nontemporal_store(z, (f32x4*)outp);
        __builtin_nontemporal_store(z, (f32x4*)(outp + 4));
        return;
    }

    // separately-rounded mul then add (no FMA) — floor() is discontinuous
    float x = __fadd_rn(__fmul_rn((float)cc, map_w), bz0x);
    float y = __fadd_rn(__fmul_rn((float)rr, map_h), bz0y);

    float x0f = floorf(x), y0f = floorf(y);
    int ix0 = min(max((int)x0f,     0), 63);
    int ix1 = min(max((int)x0f + 1, 0), 63);
    int iy0 = min(max((int)y0f,     0), 63);
    int iy1 = min(max((int)y0f + 1, 0), 63);

    const float* img = fmap + ((size_t)(tb >> 5)) * (64 * 64 * 128) + (ch8 << 3);
    const float* pa = img + (iy0 * 64 + ix0) * 128;
    const float* pb = img + (iy0 * 64 + ix1) * 128;
    const float* pc = img + (iy1 * 64 + ix0) * 128;
    const float* pd = img + (iy1 * 64 + ix1) * 128;
    f32x4 Ia0 = *(const f32x4*)pa,       Ia1 = *(const f32x4*)(pa + 4);
    f32x4 Ib0 = *(const f32x4*)pb,       Ib1 = *(const f32x4*)(pb + 4);
    f32x4 Ic0 = *(const f32x4*)pc,       Ic1 = *(const f32x4*)(pc + 4);
    f32x4 Id0 = *(const f32x4*)pd,       Id1 = *(const f32x4*)(pd + 4);

    float x0v = (float)ix0, x1v = (float)ix1;
    float y0v = (float)iy0, y1v = (float)iy1;
    float wa = (x1v - x) * (y1v - y);
    float wb = (x1v - x) * (y - y0v);
    float wc = (x - x0v) * (y1v - y);
    float wd = (x - x0v) * (y - y0v);

    f32x4 o0, o1;
    o0.x = (Ia0.x * wa + Ib0.x * wb + Ic0.x * wc + Id0.x * wd) * mask;
    o0.y = (Ia0.y * wa + Ib0.y * wb + Ic0.y * wc + Id0.y * wd) * mask;
    o0.z = (Ia0.z * wa + Ib0.z * wb + Ic0.z * wc + Id0.z * wd) * mask;
    o0.w = (Ia0.w * wa + Ib0.w * wb + Ic0.w * wc + Id0.w * wd) * mask;
    o1.x = (Ia1.x * wa + Ib1.x * wb + Ic1.x * wc + Id1.x * wd) * mask;
    o1.y = (Ia1.y * wa + Ib1.y * wb + Ic1.y * wc + Id1.y * wd) * mask;
    o1.z = (Ia1.z * wa + Ib1.z * wb + Ic1.z * wc + Id1.z * wd) * mask;
    o1.w = (Ia1.w * wa + Ib1.w * wb + Ic1.w * wc + Id1.w * wd) * mask;
    __builtin_nontemporal_store(o0, (f32x4*)outp);
    __builtin_nontemporal_store(o1, (f32x4*)(outp + 4));
}

// ---------------------------------------------------------------------------
extern "C" void kernel_launch(void* const* d_in, const int* in_sizes, int n_in,
                              void* d_out, int out_size, void* d_ws, size_t ws_size,
                              hipStream_t stream) {
    const float* fmap = (const float*)d_in[0];   // (4,64,64,128)
    const float* bbox = (const float*)d_in[1];   // (4,64,64,5)
    float* out = (float*)d_out;

    // output layout (flat, return order):
    //   nms_boxes (4,32,4)        =       512
    //   h_roi     (4,32,8,64,128) = 8,388,608
    //   widths    (4,32)          =       128
    //   v_roi     (4,32,64,8,128) = 8,388,608
    //   heights   (4,32)          =       128
    float* out_nms = out;
    float* out_h   = out + 512;
    float* out_w   = out_h + ROI_N;
    float* out_v   = out_w + 128;
    float* out_hh  = out_v + ROI_N;

    float* params = (float*)d_ws;   // [2][128][8] floats = 8 KB

    nms_kernel<<<NB, 256, 0, stream>>>(bbox, out_nms, params, out_w, out_hh);
    roi_kernel<<<8192, 256, 0, stream>>>(fmap, params, out_h, out_v);
}